// Round 4
// baseline (87.935 us; speedup 1.0000x reference)
//
#include <hip/hip_runtime.h>

#define B 32
#define L 200
#define DIN 64
#define H 64
#define A 36
#define IPB 4

typedef __attribute__((ext_vector_type(8))) short short8;   // bf16 MFMA fragment
typedef __attribute__((ext_vector_type(4))) float floatx4;  // MFMA accumulator

static __device__ __forceinline__ short f2bf(float f) {
    union { float f; unsigned u; } v; v.f = f;
    unsigned r = (v.u + 0x7FFF + ((v.u >> 16) & 1)) >> 16;  // RNE
    return (short)r;
}
static __device__ __forceinline__ float bf2f(short s) {
    union { unsigned u; float f; } v; v.u = ((unsigned)(unsigned short)s) << 16;
    return v.f;
}

// Kernel 1: h = x@ln_w + ln_b ; store h (f32), h_bf16 pre-swizzled, cc = h@w1b.
// 256 thr = 4 waves; each wave computes TWO consecutive rows (2 indep FMA chains,
// shared ln_w loads). 800 blocks.
__global__ __launch_bounds__(256) void prep_kernel(
    const float* __restrict__ x, const float* __restrict__ ln_w,
    const float* __restrict__ ln_b, const float* __restrict__ w1,
    float* __restrict__ h_out, float* __restrict__ cc_out, short* __restrict__ hb16_out)
{
    int wave = threadIdx.x >> 6;
    int lane = threadIdx.x & 63;
    int bl0 = __builtin_amdgcn_readfirstlane(blockIdx.x * 8 + wave * 2);
    const float* x0 = x + (size_t)bl0 * DIN;
    const float* x1 = x0 + DIN;
    float acc0 = ln_b[lane], acc1 = acc0;
    #pragma unroll
    for (int d = 0; d < DIN; ++d) {
        float w = ln_w[d * H + lane];          // coalesced, shared by both rows
        acc0 = fmaf(x0[d], w, acc0);           // x0/x1 uniform -> s_load
        acc1 = fmaf(x1[d], w, acc1);
    }
    __shared__ float hrow[IPB][2][H];
    hrow[wave][0][lane] = acc0;
    hrow[wave][1][lane] = acc1;
    h_out[(size_t)bl0 * H + lane] = acc0;
    h_out[(size_t)(bl0 + 1) * H + lane] = acc1;
    int j0 = bl0 % L, j1 = (bl0 + 1) % L;
    hb16_out[(size_t)bl0 * H + (lane ^ ((j0 & 7) << 3))] = f2bf(acc0);
    hb16_out[(size_t)(bl0 + 1) * H + (lane ^ ((j1 & 7) << 3))] = f2bf(acc1);
    if (lane < A) {
        float s0 = 0.f, s1 = 0.f;
        #pragma unroll
        for (int hh = 0; hh < H; ++hh) {
            float w = w1[(H + hh) * A + lane];  // w1b
            s0 = fmaf(hrow[wave][0][hh], w, s0);
            s1 = fmaf(hrow[wave][1][hh], w, s1);
        }
        cc_out[(size_t)bl0 * A + lane] = s0;
        cc_out[(size_t)(bl0 + 1) * A + lane] = s1;
    }
}

// Kernel 2: triangle-paired. Block = (b, bg), bg in 0..24; wave w owns
// i_lo = 4*bg+w (0..99) AND i_hi = 199-i_lo (100..199) -> constant work/wave.
__global__ __launch_bounds__(256) void score_kernel(
    const float* __restrict__ h, const short* __restrict__ hb16,
    const float* __restrict__ cc, const float* __restrict__ w1,
    const float* __restrict__ b1, const float* __restrict__ w2,
    const float* __restrict__ b2, float* __restrict__ out)
{
    int blk = blockIdx.x;
    int b  = blk / 25;
    int bg = blk - b * 25;
    int wave = threadIdx.x >> 6;
    int lane = threadIdx.x & 63;
    int i_lo = __builtin_amdgcn_readfirstlane(bg * 4 + wave);
    int i_hi = 199 - i_lo;
    int iv[2] = {i_lo, i_hi};
    int l15 = lane & 15, l4 = lane >> 4;

    __shared__ __align__(16) short tile[64 * 64];   // bf16, rows pre-swizzled
    __shared__ __align__(16) float slds[IPB][2][68];

    const short* hb16b = hb16 + (size_t)b * L * H;
    float b2v = b2[0];
    float w2v[3];
    #pragma unroll
    for (int n = 0; n < 3; ++n) {
        int c = n * 16 + l15;
        w2v[n] = (c < A) ? w2[c] : 0.f;
    }

    // per-i constants: B_i fragments (w1a + h_i*w1c folded), cb (cc+b1 folded)
    float cbv[2][3];
    short8 bfrag[2][2][3];
    #pragma unroll
    for (int ii = 0; ii < 2; ++ii) {
        int i = iv[ii];
        const float* hi    = h + ((size_t)b * L + i) * H;    // uniform -> s_load
        const float* ccrow = cc + ((size_t)b * L + i) * A;
        #pragma unroll
        for (int n = 0; n < 3; ++n) {
            int c = n * 16 + l15;
            cbv[ii][n] = (c < A) ? (ccrow[c] + b1[c]) : 0.f;
        }
        #pragma unroll
        for (int s = 0; s < 2; ++s) {
            float hik[8];
            #pragma unroll
            for (int e = 0; e < 8; ++e) hik[e] = hi[s * 32 + l4 * 8 + e];
            #pragma unroll
            for (int n = 0; n < 3; ++n) {
                int c = n * 16 + l15;
                bool cv = c < A;
                #pragma unroll
                for (int e = 0; e < 8; ++e) {
                    int k = s * 32 + l4 * 8 + e;
                    float wc = cv ? w1[(2 * H + k) * A + c] : 0.f;  // w1c
                    float wa = cv ? w1[k * A + c] : 0.f;            // w1a
                    bfrag[ii][s][n][e] = f2bf(fmaf(hik[e], wc, wa));
                }
            }
        }
    }

    float oacc[2][4];
    #pragma unroll
    for (int ii = 0; ii < 2; ++ii)
        #pragma unroll
        for (int q = 0; q < 4; ++q) oacc[ii][q] = 0.f;

    int tmax = (200 - 4 * bg + 63) / 64;   // block-uniform tile count (covers i_hi_max)

    for (int t = 0; t < tmax; ++t) {
        int j0 = t * 64;
        // stage tile: wave w copies rows w*16..w*16+15 (linear; data pre-swizzled)
        #pragma unroll
        for (int it = 0; it < 2; ++it) {
            int r = wave * 16 + it * 8 + (lane >> 3);
            int j = j0 + r; if (j > L - 1) j = L - 1;
            const int4* src = (const int4*)(hb16b + (size_t)j * H) + (lane & 7);
            *((int4*)tile + r * 8 + (lane & 7)) = *src;
        }
        __syncthreads();

        #pragma unroll
        for (int ii = 0; ii < 2; ++ii) {
            int irel = iv[ii] - j0;
            if (irel >= 0) {                                   // wave-uniform
                int mmax = ((irel < 63 ? irel : 63) >> 4) + 1;
                for (int m = 0; m < mmax; ++m) {
                    int row = m * 16 + l15;
                    const short* arow = tile + row * H;
                    int sw = (row & 7) << 3;
                    short8 af0 = *(const short8*)(arow + ((0  + l4 * 8) ^ sw));
                    short8 af1 = *(const short8*)(arow + ((32 + l4 * 8) ^ sw));
                    floatx4 a0 = {cbv[ii][0], cbv[ii][0], cbv[ii][0], cbv[ii][0]};
                    floatx4 a1 = {cbv[ii][1], cbv[ii][1], cbv[ii][1], cbv[ii][1]};
                    floatx4 a2 = {cbv[ii][2], cbv[ii][2], cbv[ii][2], cbv[ii][2]};
                    a0 = __builtin_amdgcn_mfma_f32_16x16x32_bf16(af0, bfrag[ii][0][0], a0, 0, 0, 0);
                    a1 = __builtin_amdgcn_mfma_f32_16x16x32_bf16(af0, bfrag[ii][0][1], a1, 0, 0, 0);
                    a2 = __builtin_amdgcn_mfma_f32_16x16x32_bf16(af0, bfrag[ii][0][2], a2, 0, 0, 0);
                    a0 = __builtin_amdgcn_mfma_f32_16x16x32_bf16(af1, bfrag[ii][1][0], a0, 0, 0, 0);
                    a1 = __builtin_amdgcn_mfma_f32_16x16x32_bf16(af1, bfrag[ii][1][1], a1, 0, 0, 0);
                    a2 = __builtin_amdgcn_mfma_f32_16x16x32_bf16(af1, bfrag[ii][1][2], a2, 0, 0, 0);
                    float sp[4];
                    #pragma unroll
                    for (int r = 0; r < 4; ++r) {
                        float v0 = a0[r], v1 = a1[r], v2 = a2[r];
                        v0 = v0 > 0.f ? v0 : 0.01f * v0;
                        v1 = v1 > 0.f ? v1 : 0.01f * v1;
                        v2 = v2 > 0.f ? v2 : 0.01f * v2;
                        sp[r] = v0 * w2v[0] + v1 * w2v[1] + v2 * w2v[2];
                    }
                    #pragma unroll
                    for (int d = 1; d < 16; d <<= 1) {
                        #pragma unroll
                        for (int r = 0; r < 4; ++r) sp[r] += __shfl_xor(sp[r], d, 64);
                    }
                    if (l15 == 0) {
                        #pragma unroll
                        for (int r = 0; r < 4; ++r) {
                            int jt = m * 16 + l4 * 4 + r;
                            slds[wave][ii][jt] = (jt <= irel) ? sp[r] + b2v : 0.f;
                        }
                    }
                }
                // PV: 4 independent accumulator chains
                int rmax = irel < 63 ? irel : 63;
                for (int rb = 0; rb <= rmax; rb += 4) {
                    floatx4 sv = *(const floatx4*)&slds[wave][ii][rb];
                    #pragma unroll
                    for (int q = 0; q < 4; ++q) {
                        int r = rb + q;
                        if (r > rmax) break;
                        short hbv = tile[r * H + (lane ^ ((r & 7) << 3))];
                        oacc[ii][q] = fmaf(sv[q], bf2f(hbv), oacc[ii][q]);
                    }
                }
            }
        }
        __syncthreads();   // protect tile before next staging
    }

    #pragma unroll
    for (int ii = 0; ii < 2; ++ii) {
        float s = (oacc[ii][0] + oacc[ii][1]) + (oacc[ii][2] + oacc[ii][3]);
        out[((size_t)b * L + iv[ii]) * H + lane] = s;
    }
}

extern "C" void kernel_launch(void* const* d_in, const int* in_sizes, int n_in,
                              void* d_out, int out_size, void* d_ws, size_t ws_size,
                              hipStream_t stream) {
    const float* x    = (const float*)d_in[0];
    const float* ln_w = (const float*)d_in[1];
    const float* ln_b = (const float*)d_in[2];
    const float* w1   = (const float*)d_in[3];
    const float* b1   = (const float*)d_in[4];
    const float* w2   = (const float*)d_in[5];
    const float* b2   = (const float*)d_in[6];
    float* out = (float*)d_out;

    float* h_ws  = (float*)d_ws;                           // B*L*H f32
    float* cc_ws = h_ws + (size_t)B * L * H;               // B*L*A f32
    short* hb16_ws = (short*)(cc_ws + (size_t)B * L * A);  // B*L*H bf16 (pre-swizzled)

    prep_kernel<<<(B * L) / 8, 256, 0, stream>>>(x, ln_w, ln_b, w1, h_ws, cc_ws, hb16_ws);
    score_kernel<<<B * 25, 256, 0, stream>>>(h_ws, hb16_ws, cc_ws, w1, b1, w2, b2, out);
}

// Round 5
// 37.879 us; speedup vs baseline: 2.3215x; 2.3215x over previous
//
#include <hip/hip_runtime.h>

#define B 32
#define L 200
#define DIN 64
#define H 64
#define A 36

typedef __attribute__((ext_vector_type(8))) short short8;   // bf16 MFMA fragment
typedef __attribute__((ext_vector_type(4))) float floatx4;  // MFMA accumulator
typedef __attribute__((ext_vector_type(8))) float floatx8;

static __device__ __forceinline__ short f2bf(float f) {
    union { float f; unsigned u; } v; v.f = f;
    unsigned r = (v.u + 0x7FFF + ((v.u >> 16) & 1)) >> 16;  // RNE
    return (short)r;
}
static __device__ __forceinline__ float bf2f(short s) {
    union { unsigned u; float f; } v; v.u = ((unsigned)(unsigned short)s) << 16;
    return v.f;
}

// Kernel 1: h = x@ln_w + ln_b ; h f32, hb16 pre-swizzled, cc = h@w1b.
// Block 0 additionally reorders w1a/w1c into MFMA-fragment order (f32).
__global__ __launch_bounds__(256) void prep_kernel(
    const float* __restrict__ x, const float* __restrict__ ln_w,
    const float* __restrict__ ln_b, const float* __restrict__ w1,
    float* __restrict__ h_out, float* __restrict__ cc_out, short* __restrict__ hb16_out,
    float* __restrict__ w1a_r, float* __restrict__ w1c_r)
{
    int wave = threadIdx.x >> 6;
    int lane = threadIdx.x & 63;
    int bl0 = __builtin_amdgcn_readfirstlane(blockIdx.x * 8 + wave * 2);
    const float* x0 = x + (size_t)bl0 * DIN;
    const float* x1 = x0 + DIN;
    float acc0 = ln_b[lane], acc1 = acc0;
    #pragma unroll
    for (int d = 0; d < DIN; ++d) {
        float w = ln_w[d * H + lane];          // coalesced, shared by both rows
        acc0 = fmaf(x0[d], w, acc0);           // x0/x1 uniform -> s_load
        acc1 = fmaf(x1[d], w, acc1);
    }
    __shared__ float hrow[4][2][H];
    hrow[wave][0][lane] = acc0;
    hrow[wave][1][lane] = acc1;
    h_out[(size_t)bl0 * H + lane] = acc0;
    h_out[(size_t)(bl0 + 1) * H + lane] = acc1;
    int j0 = bl0 % L, j1 = (bl0 + 1) % L;
    hb16_out[(size_t)bl0 * H + (lane ^ ((j0 & 7) << 3))] = f2bf(acc0);
    hb16_out[(size_t)(bl0 + 1) * H + (lane ^ ((j1 & 7) << 3))] = f2bf(acc1);
    if (lane < A) {
        float s0 = 0.f, s1 = 0.f;
        #pragma unroll
        for (int hh = 0; hh < H; ++hh) {
            float w = w1[(H + hh) * A + lane];  // w1b
            s0 = fmaf(hrow[wave][0][hh], w, s0);
            s1 = fmaf(hrow[wave][1][hh], w, s1);
        }
        cc_out[(size_t)bl0 * A + lane] = s0;
        cc_out[(size_t)(bl0 + 1) * A + lane] = s1;
    }
    if (blockIdx.x == 0) {
        // fragment-order tables: idx = ((s*3+n)*64 + lane)*8 + e
        for (int idx = threadIdx.x; idx < 2 * 3 * 64 * 8; idx += 256) {
            int e = idx & 7, ln = (idx >> 3) & 63, sn = idx >> 9;
            int s = sn / 3, n = sn - 3 * s;
            int k = s * 32 + (ln >> 4) * 8 + e;
            int c = n * 16 + (ln & 15);
            w1a_r[idx] = (c < A) ? w1[k * A + c] : 0.f;
            w1c_r[idx] = (c < A) ? w1[(2 * H + k) * A + c] : 0.f;
        }
    }
}

// Kernel 2: block=(b,bg), bg 0..49; wave w owns i = bg + 50w. All 200 rows staged
// once via global_load_lds; one barrier; waves loop independently, no more barriers.
__global__ __launch_bounds__(256) void score_kernel(
    const float* __restrict__ h, const short* __restrict__ hb16,
    const float* __restrict__ cc, const float* __restrict__ w1a_r,
    const float* __restrict__ w1c_r, const float* __restrict__ b1,
    const float* __restrict__ w2, const float* __restrict__ b2,
    float* __restrict__ out)
{
    int blk = blockIdx.x;
    int b  = blk / 50;
    int bg = blk - b * 50;
    int wave = threadIdx.x >> 6;
    int lane = threadIdx.x & 63;
    int i = __builtin_amdgcn_readfirstlane(bg + 50 * wave);
    int l15 = lane & 15, l4 = lane >> 4;

    __shared__ __align__(16) short tile[208 * 64];  // all 200 rows (+8 pad), pre-swizzled
    __shared__ __align__(16) float slds[4][16];

    const short* hb16b = hb16 + (size_t)b * L * H;

    // ---- stage: 26 chunks x 8 rows, global_load_lds width 16 (linear LDS dest) ----
    for (int c = wave; c < 26; c += 4) {
        int j = (c < 25) ? (c * 8 + (lane >> 3)) : (L - 1);   // pad rows: row-199 data
        const short* src = hb16b + (size_t)j * H + (lane & 7) * 8;
        __builtin_amdgcn_global_load_lds(
            (const __attribute__((address_space(1))) void*)src,
            (__attribute__((address_space(3))) void*)&tile[c * 512],
            16, 0, 0);
    }

    // ---- prologue (overlaps staging): B_i fragments from reordered tables ----
    const float* hi    = h + ((size_t)b * L + i) * H;     // uniform -> s_load
    const float* ccrow = cc + ((size_t)b * L + i) * A;
    float b2v = b2[0];
    float w2v[3], cbv[3];
    #pragma unroll
    for (int n = 0; n < 3; ++n) {
        int c = n * 16 + l15;
        w2v[n] = (c < A) ? w2[c] : 0.f;
        cbv[n] = (c < A) ? (ccrow[c] + b1[c]) : 0.f;
    }
    short8 bfrag[2][3];
    #pragma unroll
    for (int s = 0; s < 2; ++s) {
        float hik[8];
        #pragma unroll
        for (int e = 0; e < 8; ++e) hik[e] = hi[s * 32 + l4 * 8 + e];
        #pragma unroll
        for (int n = 0; n < 3; ++n) {
            floatx8 wa = *(const floatx8*)&w1a_r[(((s * 3 + n) * 64) + lane) * 8];
            floatx8 wc = *(const floatx8*)&w1c_r[(((s * 3 + n) * 64) + lane) * 8];
            #pragma unroll
            for (int e = 0; e < 8; ++e)
                bfrag[s][n][e] = f2bf(fmaf(hik[e], wc[e], wa[e]));
        }
    }
    __syncthreads();   // staging complete (drains vmcnt)

    float oacc[4] = {0.f, 0.f, 0.f, 0.f};
    int mmax = (i >> 4) + 1;   // wave-uniform

    for (int m = 0; m < mmax; ++m) {
        int row = m * 16 + l15;
        const short* arow = tile + row * 64;
        int sw = (row & 7) << 3;
        short8 af0 = *(const short8*)(arow + ((l4 * 8) ^ sw));
        short8 af1 = *(const short8*)(arow + ((32 + l4 * 8) ^ sw));
        floatx4 a0 = {cbv[0], cbv[0], cbv[0], cbv[0]};
        floatx4 a1 = {cbv[1], cbv[1], cbv[1], cbv[1]};
        floatx4 a2 = {cbv[2], cbv[2], cbv[2], cbv[2]};
        a0 = __builtin_amdgcn_mfma_f32_16x16x32_bf16(af0, bfrag[0][0], a0, 0, 0, 0);
        a1 = __builtin_amdgcn_mfma_f32_16x16x32_bf16(af0, bfrag[0][1], a1, 0, 0, 0);
        a2 = __builtin_amdgcn_mfma_f32_16x16x32_bf16(af0, bfrag[0][2], a2, 0, 0, 0);
        a0 = __builtin_amdgcn_mfma_f32_16x16x32_bf16(af1, bfrag[1][0], a0, 0, 0, 0);
        a1 = __builtin_amdgcn_mfma_f32_16x16x32_bf16(af1, bfrag[1][1], a1, 0, 0, 0);
        a2 = __builtin_amdgcn_mfma_f32_16x16x32_bf16(af1, bfrag[1][2], a2, 0, 0, 0);
        // epilogue: leaky + w2 dot, reduce over a (l15 lanes)
        float sp[4];
        #pragma unroll
        for (int r = 0; r < 4; ++r) {
            float v0 = a0[r], v1 = a1[r], v2 = a2[r];
            v0 = v0 > 0.f ? v0 : 0.01f * v0;
            v1 = v1 > 0.f ? v1 : 0.01f * v1;
            v2 = v2 > 0.f ? v2 : 0.01f * v2;
            sp[r] = v0 * w2v[0] + v1 * w2v[1] + v2 * w2v[2];
        }
        #pragma unroll
        for (int d = 1; d < 16; d <<= 1) {
            #pragma unroll
            for (int r = 0; r < 4; ++r) sp[r] += __shfl_xor(sp[r], d, 64);
        }
        if (l15 == 0) {
            #pragma unroll
            for (int r = 0; r < 4; ++r) {
                int jt = m * 16 + l4 * 4 + r;
                slds[wave][l4 * 4 + r] = (jt <= i) ? sp[r] + b2v : 0.f;
            }
        }
        // PV: 4 independent chains; masked rows contribute 0
        #pragma unroll
        for (int rb = 0; rb < 4; ++rb) {
            floatx4 sv = *(const floatx4*)&slds[wave][rb * 4];  // same-wave RAW
            #pragma unroll
            for (int q = 0; q < 4; ++q) {
                int j = m * 16 + rb * 4 + q;
                short hbv = tile[j * 64 + (lane ^ ((j & 7) << 3))];
                oacc[q] = fmaf(sv[q], bf2f(hbv), oacc[q]);
            }
        }
    }

    out[((size_t)b * L + i) * H + lane] = (oacc[0] + oacc[1]) + (oacc[2] + oacc[3]);
}

extern "C" void kernel_launch(void* const* d_in, const int* in_sizes, int n_in,
                              void* d_out, int out_size, void* d_ws, size_t ws_size,
                              hipStream_t stream) {
    const float* x    = (const float*)d_in[0];
    const float* ln_w = (const float*)d_in[1];
    const float* ln_b = (const float*)d_in[2];
    const float* w1   = (const float*)d_in[3];
    const float* b1   = (const float*)d_in[4];
    const float* w2   = (const float*)d_in[5];
    const float* b2   = (const float*)d_in[6];
    float* out = (float*)d_out;

    float* h_ws   = (float*)d_ws;                             // B*L*H f32
    float* cc_ws  = h_ws + (size_t)B * L * H;                 // B*L*A f32
    short* hb16_ws = (short*)(cc_ws + (size_t)B * L * A);     // B*L*H bf16 (pre-swizzled)
    float* w1a_r  = (float*)(hb16_ws + (size_t)B * L * H);    // 3072 f32
    float* w1c_r  = w1a_r + 3072;                             // 3072 f32

    prep_kernel<<<(B * L) / 8, 256, 0, stream>>>(x, ln_w, ln_b, w1, h_ws, cc_ws,
                                                 hb16_ws, w1a_r, w1c_r);
    score_kernel<<<B * 50, 256, 0, stream>>>(h_ws, hb16_ws, cc_ws, w1a_r, w1c_r,
                                             b1, w2, b2, out);
}

// Round 6
// 37.755 us; speedup vs baseline: 2.3291x; 1.0033x over previous
//
#include <hip/hip_runtime.h>

#define B 32
#define L 200
#define DIN 64
#define H 64
#define A 36

typedef __attribute__((ext_vector_type(8))) short short8;   // bf16 MFMA fragment
typedef __attribute__((ext_vector_type(4))) float floatx4;  // MFMA accumulator
typedef __attribute__((ext_vector_type(8))) float floatx8;

static __device__ __forceinline__ short f2bf(float f) {
    union { float f; unsigned u; } v; v.f = f;
    unsigned r = (v.u + 0x7FFF + ((v.u >> 16) & 1)) >> 16;  // RNE
    return (short)r;
}
static __device__ __forceinline__ float bf2f(short s) {
    union { unsigned u; float f; } v; v.u = ((unsigned)(unsigned short)s) << 16;
    return v.f;
}

// Kernel 1: h = x@ln_w + ln_b ; h f32, hb16 pre-swizzled, cc = h@w1b.
// 1 row per wave (1600 blocks -> 6.25 waves/SIMD), 2-way split-K ILP.
// Block 0 also reorders w1a/w1c into MFMA-fragment order (f32).
__global__ __launch_bounds__(256) void prep_kernel(
    const float* __restrict__ x, const float* __restrict__ ln_w,
    const float* __restrict__ ln_b, const float* __restrict__ w1,
    float* __restrict__ h_out, float* __restrict__ cc_out, short* __restrict__ hb16_out,
    float* __restrict__ w1a_r, float* __restrict__ w1c_r)
{
    int wave = threadIdx.x >> 6;
    int lane = threadIdx.x & 63;
    int bl = __builtin_amdgcn_readfirstlane(blockIdx.x * 4 + wave);
    const float* xr = x + (size_t)bl * DIN;
    float p0 = ln_b[lane], p1 = 0.f;
    #pragma unroll
    for (int d = 0; d < DIN; d += 2) {
        p0 = fmaf(xr[d],     ln_w[d * H + lane],       p0);   // xr uniform -> s_load
        p1 = fmaf(xr[d + 1], ln_w[(d + 1) * H + lane], p1);
    }
    float acc = p0 + p1;
    __shared__ float hrow[4][H];
    hrow[wave][lane] = acc;
    h_out[(size_t)bl * H + lane] = acc;
    int j = bl % L;
    hb16_out[(size_t)bl * H + (lane ^ ((j & 7) << 3))] = f2bf(acc);
    if (lane < A) {
        float s0 = 0.f, s1 = 0.f;
        #pragma unroll
        for (int hh = 0; hh < H; hh += 2) {
            s0 = fmaf(hrow[wave][hh],     w1[(H + hh) * A + lane],     s0);   // w1b
            s1 = fmaf(hrow[wave][hh + 1], w1[(H + hh + 1) * A + lane], s1);
        }
        cc_out[(size_t)bl * A + lane] = s0 + s1;
    }
    if (blockIdx.x == 0) {
        // fragment-order tables: idx = ((s*3+n)*64 + lane)*8 + e
        for (int idx = threadIdx.x; idx < 2 * 3 * 64 * 8; idx += 256) {
            int e = idx & 7, ln = (idx >> 3) & 63, sn = idx >> 9;
            int s = sn / 3, n = sn - 3 * s;
            int k = s * 32 + (ln >> 4) * 8 + e;
            int c = n * 16 + (ln & 15);
            w1a_r[idx] = (c < A) ? w1[k * A + c] : 0.f;
            w1c_r[idx] = (c < A) ? w1[(2 * H + k) * A + c] : 0.f;
        }
    }
}

// Kernel 2: block=(b,bg), bg 0..49; wave w owns i = bg + 50w. All 200 rows staged
// once (global_load_lds w16, linear LDS dest, pre-swizzled global); one barrier.
// MFMA roles: A = folded B_i (M=a), B = h-tile (N=j)  ->  C row=a, col=j:
// a-reduction is in-lane (12 fma) + 2 shfl_xor rounds (vs 4-round 16-shfl before).
__global__ __launch_bounds__(256) void score_kernel(
    const float* __restrict__ h, const short* __restrict__ hb16,
    const float* __restrict__ cc, const float* __restrict__ w1a_r,
    const float* __restrict__ w1c_r, const float* __restrict__ b1,
    const float* __restrict__ w2, const float* __restrict__ b2,
    float* __restrict__ out)
{
    int blk = blockIdx.x;
    int b  = blk / 50;
    int bg = blk - b * 50;
    int wave = threadIdx.x >> 6;
    int lane = threadIdx.x & 63;
    int i = __builtin_amdgcn_readfirstlane(bg + 50 * wave);
    int l15 = lane & 15, l4 = lane >> 4;

    __shared__ __align__(16) short tile[208 * 64];  // 200 rows + 8 pad, pre-swizzled
    __shared__ __align__(16) float slds[4][16];

    const short* hb16b = hb16 + (size_t)b * L * H;

    // ---- stage: 26 chunks x 8 rows, global_load_lds width 16 ----
    for (int c = wave; c < 26; c += 4) {
        int j = (c < 25) ? (c * 8 + (lane >> 3)) : (L - 1);   // pad rows: row-199 data
        const short* src = hb16b + (size_t)j * H + (lane & 7) * 8;
        __builtin_amdgcn_global_load_lds(
            (const __attribute__((address_space(1))) void*)src,
            (__attribute__((address_space(3))) void*)&tile[c * 512],
            16, 0, 0);
    }

    // ---- prologue (overlaps staging) ----
    const float* hi    = h + ((size_t)b * L + i) * H;     // uniform -> s_load
    const float* ccrow = cc + ((size_t)b * L + i) * A;
    float b2v = b2[0];
    float w2v[3][4], cbv[3][4];
    #pragma unroll
    for (int n = 0; n < 3; ++n) {
        #pragma unroll
        for (int r = 0; r < 4; ++r) {
            int a = n * 16 + l4 * 4 + r;       // this lane's C row for tile n, reg r
            bool av = a < A;
            w2v[n][r] = av ? w2[a] : 0.f;
            cbv[n][r] = av ? (ccrow[a] + b1[a]) : 0.f;
        }
    }
    short8 afrag[2][3];                        // A-operand: B_i[a = n*16+l15][k]
    #pragma unroll
    for (int s = 0; s < 2; ++s) {
        float hik[8];
        #pragma unroll
        for (int e = 0; e < 8; ++e) hik[e] = hi[s * 32 + l4 * 8 + e];
        #pragma unroll
        for (int n = 0; n < 3; ++n) {
            floatx8 wa = *(const floatx8*)&w1a_r[(((s * 3 + n) * 64) + lane) * 8];
            floatx8 wc = *(const floatx8*)&w1c_r[(((s * 3 + n) * 64) + lane) * 8];
            #pragma unroll
            for (int e = 0; e < 8; ++e)
                afrag[s][n][e] = f2bf(fmaf(hik[e], wc[e], wa[e]));
        }
    }
    __syncthreads();   // staging complete

    float oacc[4] = {0.f, 0.f, 0.f, 0.f};
    int mmax = (i >> 4) + 1;   // wave-uniform

    for (int m = 0; m < mmax; ++m) {
        // B-fragment: h[j = m*16+l15][k], swizzled read
        int row = m * 16 + l15;
        const short* brow = tile + row * 64;
        int sw = (l15 & 7) << 3;
        short8 bf0 = *(const short8*)(brow + ((l4 * 8) ^ sw));
        short8 bf1 = *(const short8*)(brow + ((32 + l4 * 8) ^ sw));
        floatx4 c0 = {cbv[0][0], cbv[0][1], cbv[0][2], cbv[0][3]};
        floatx4 c1 = {cbv[1][0], cbv[1][1], cbv[1][2], cbv[1][3]};
        floatx4 c2 = {cbv[2][0], cbv[2][1], cbv[2][2], cbv[2][3]};
        c0 = __builtin_amdgcn_mfma_f32_16x16x32_bf16(afrag[0][0], bf0, c0, 0, 0, 0);
        c1 = __builtin_amdgcn_mfma_f32_16x16x32_bf16(afrag[0][1], bf0, c1, 0, 0, 0);
        c2 = __builtin_amdgcn_mfma_f32_16x16x32_bf16(afrag[0][2], bf0, c2, 0, 0, 0);
        c0 = __builtin_amdgcn_mfma_f32_16x16x32_bf16(afrag[1][0], bf1, c0, 0, 0, 0);
        c1 = __builtin_amdgcn_mfma_f32_16x16x32_bf16(afrag[1][1], bf1, c1, 0, 0, 0);
        c2 = __builtin_amdgcn_mfma_f32_16x16x32_bf16(afrag[1][2], bf1, c2, 0, 0, 0);
        // epilogue: leaky + w2 dot fully in-lane over (n,r), then 2 shfl rounds over l4
        float sp = 0.f;
        #pragma unroll
        for (int r = 0; r < 4; ++r) {
            float v0 = c0[r], v1 = c1[r], v2 = c2[r];
            float a0 = fmaf(0.01f, fminf(v0, 0.f), fmaxf(v0, 0.f));
            float a1 = fmaf(0.01f, fminf(v1, 0.f), fmaxf(v1, 0.f));
            float a2 = fmaf(0.01f, fminf(v2, 0.f), fmaxf(v2, 0.f));
            sp = fmaf(a0, w2v[0][r], sp);
            sp = fmaf(a1, w2v[1][r], sp);
            sp = fmaf(a2, w2v[2][r], sp);
        }
        sp += __shfl_xor(sp, 16, 64);
        sp += __shfl_xor(sp, 32, 64);          // all lanes: score[j = l15]
        float sc = (row <= i) ? sp + b2v : 0.f;
        if (l4 == 0) slds[wave][l15] = sc;
        // PV: 4 independent chains; masked rows contribute 0
        #pragma unroll
        for (int rb = 0; rb < 4; ++rb) {
            floatx4 sv = *(const floatx4*)&slds[wave][rb * 4];  // same-wave RAW
            #pragma unroll
            for (int q = 0; q < 4; ++q) {
                int j = m * 16 + rb * 4 + q;
                short hbv = tile[j * 64 + (lane ^ ((j & 7) << 3))];
                oacc[q] = fmaf(sv[q], bf2f(hbv), oacc[q]);
            }
        }
    }

    out[((size_t)b * L + i) * H + lane] = (oacc[0] + oacc[1]) + (oacc[2] + oacc[3]);
}

extern "C" void kernel_launch(void* const* d_in, const int* in_sizes, int n_in,
                              void* d_out, int out_size, void* d_ws, size_t ws_size,
                              hipStream_t stream) {
    const float* x    = (const float*)d_in[0];
    const float* ln_w = (const float*)d_in[1];
    const float* ln_b = (const float*)d_in[2];
    const float* w1   = (const float*)d_in[3];
    const float* b1   = (const float*)d_in[4];
    const float* w2   = (const float*)d_in[5];
    const float* b2   = (const float*)d_in[6];
    float* out = (float*)d_out;

    float* h_ws   = (float*)d_ws;                             // B*L*H f32
    float* cc_ws  = h_ws + (size_t)B * L * H;                 // B*L*A f32
    short* hb16_ws = (short*)(cc_ws + (size_t)B * L * A);     // B*L*H bf16 (pre-swizzled)
    float* w1a_r  = (float*)(hb16_ws + (size_t)B * L * H);    // 3072 f32
    float* w1c_r  = w1a_r + 3072;                             // 3072 f32

    prep_kernel<<<(B * L) / 4, 256, 0, stream>>>(x, ln_w, ln_b, w1, h_ws, cc_ws,
                                                 hb16_ws, w1a_r, w1c_r);
    score_kernel<<<B * 50, 256, 0, stream>>>(h_ws, hb16_ws, cc_ws, w1a_r, w1c_r,
                                             b1, w2, b2, out);
}